// Round 6
// baseline (491.385 us; speedup 1.0000x reference)
//
#include <hip/hip_runtime.h>
#include <math.h>

#define NB 4096
#define NS 50
#define NH 64
#define NITEM 40000

typedef float f4 __attribute__((ext_vector_type(4)));

#define NTOT   4096                 // total blocks (256 thr)
#define NZERO  3072                 // 3 of every 4 blocks are zero-role
#define TOTAL4 ((long long)NB * NITEM / 4)   // 40,960,000 float4

// Fused kernel, interleaved roles (fix for R1's convoy + NT-store BW loss):
//   blockIdx % 4 != 0  -> zero role: grid-stride PLAIN float4 stores over the
//                         655 MB output — byte-for-byte the access pattern of
//                         the runtime's fillBufferAligned, which measures
//                         6.6 TB/s on this chip (our NT stores never got
//                         close; R5's runtime memset was launch-limited).
//   blockIdx % 4 == 0  -> compute role: 4 waves, one row b per wave; lane i
//                         owns output-dim i (Ur[i,:] in 64 VGPRs), all_memory
//                         row addresses wave-uniform; in-wave shfl softmax;
//                         probs -> d_ws.
// Roles interleave in dispatch order, so ~3/4 of resident blocks are storing
// from t=0 and compute (~20 us total) hides fully under the ~105 us write wall.
__global__ __launch_bounds__(256) void fused_zero_probs(
    const float* __restrict__ all_memory,   // [NB, NS, NH]
    const float* __restrict__ last_memory,  // [NB, NH]
    const float* __restrict__ Wr,           // [NH, NH]
    const float* __restrict__ Ur,           // [NH, NH]
    const float* __restrict__ Vr_w,         // [1, NH]
    float* __restrict__ out,                // [NB, NITEM]
    float* __restrict__ probs)              // [NB, NS] (workspace)
{
    const int bid = blockIdx.x;
    const int tid = (int)threadIdx.x;
    const int q = bid >> 2;
    const int r = bid & 3;

    if (r != 0) {
        // ---------------- zero role ----------------
        const int zid = q * 3 + (r - 1);            // 0 .. NZERO-1
        f4* o4 = (f4*)out;
        const f4 z = (f4)(0.0f);
        const long long stride = (long long)NZERO * 256;
        for (long long i = (long long)zid * 256 + tid; i < TOTAL4; i += stride)
            o4[i] = z;                              // plain store (L2 path)
        return;
    }

    // ---------------- compute role: one wave per row ----------------
    const int lane = tid & 63;
    const int warp = __builtin_amdgcn_readfirstlane(tid >> 6);
    const int b = q * 4 + warp;                     // wave-uniform

    float ur[NH];
    {
        const float* urow = Ur + lane * NH;
        #pragma unroll
        for (int h = 0; h < NH; h += 4) {
            float4 u = *(const float4*)(urow + h);
            ur[h] = u.x; ur[h + 1] = u.y; ur[h + 2] = u.z; ur[h + 3] = u.w;
        }
    }
    float lm = 0.f;
    {
        const float* lrow = last_memory + b * NH;   // wave-uniform
        const float* wrow = Wr + lane * NH;
        #pragma unroll
        for (int h = 0; h < NH; h += 4) {
            float4 w = *(const float4*)(wrow + h);
            float4 l = *(const float4*)(lrow + h);
            lm += w.x * l.x + w.y * l.y + w.z * l.z + w.w * l.w;
        }
    }
    const float vw = Vr_w[lane];
    const float* am = all_memory + (long long)b * (NS * NH);

    float myscore = 0.f;
    for (int s = 0; s < NS; ++s) {
        const float* arow = am + s * NH;            // wave-uniform
        float v0 = 0.f, v1 = 0.f, v2 = 0.f, v3 = 0.f;
        #pragma unroll
        for (int h = 0; h < NH; h += 4) {
            float4 a = *(const float4*)(arow + h);
            v0 += a.x * ur[h];
            v1 += a.y * ur[h + 1];
            v2 += a.z * ur[h + 2];
            v3 += a.w * ur[h + 3];
        }
        // Vr_b dropped: constant score shift cancels in softmax.
        float t = tanhf(lm + ((v0 + v1) + (v2 + v3))) * vw;
        #pragma unroll
        for (int off = 32; off >= 1; off >>= 1)
            t += __shfl_xor(t, off, 64);
        myscore = (lane == s) ? t : myscore;
    }

    // in-wave softmax over lanes 0..NS-1
    float sc = (lane < NS) ? myscore : -INFINITY;
    float m = sc;
    #pragma unroll
    for (int off = 32; off >= 1; off >>= 1)
        m = fmaxf(m, __shfl_xor(m, off, 64));
    float e = (lane < NS) ? expf(sc - m) : 0.f;
    float d = e;
    #pragma unroll
    for (int off = 32; off >= 1; off >>= 1)
        d += __shfl_xor(d, off, 64);
    if (lane < NS)
        probs[b * NS + lane] = e / d;
}

// One thread per (b, s): atomicAdd accumulates duplicate items exactly like
// the reference's .at[].add. Runs after all zeroing (separate dispatch).
__global__ __launch_bounds__(256) void scatter_k(
    const float* __restrict__ probs,
    const int* __restrict__ seq,
    float* __restrict__ out)
{
    int t = blockIdx.x * 256 + threadIdx.x;
    if (t >= NB * NS) return;
    int b = t / NS;
    float p = probs[t];
    int item = seq[t];
    atomicAdd(out + (long long)b * NITEM + item, p);
}

extern "C" void kernel_launch(void* const* d_in, const int* in_sizes, int n_in,
                              void* d_out, int out_size, void* d_ws, size_t ws_size,
                              hipStream_t stream) {
    const float* all_memory  = (const float*)d_in[0];
    const float* last_memory = (const float*)d_in[1];
    const float* Wr          = (const float*)d_in[2];
    const float* Ur          = (const float*)d_in[3];
    const float* Vr_w        = (const float*)d_in[4];
    // d_in[5] = Vr_b: constant shift of all scores, cancels in softmax.
    const int*   seq         = (const int*)d_in[6];
    float* out   = (float*)d_out;
    float* probs = (float*)d_ws;   // NB*NS floats = 819,200 B

    fused_zero_probs<<<NTOT, 256, 0, stream>>>(all_memory, last_memory, Wr, Ur,
                                               Vr_w, out, probs);
    scatter_k<<<(NB * NS + 255) / 256, 256, 0, stream>>>(probs, seq, out);
}

// Round 7
// 209.282 us; speedup vs baseline: 2.3480x; 2.3480x over previous
//
#include <hip/hip_runtime.h>
#include <math.h>

#define NB 4096
#define NS 50
#define NH 64
#define NITEM 40000
#define ROWS_PER_BLOCK 2
#define NBLK (NB / ROWS_PER_BLOCK)          // 2048 blocks
#define CHUNK4 (NITEM * ROWS_PER_BLOCK / 4) // 20000 float4 = 320,000 B, contiguous

typedef float f4 __attribute__((ext_vector_type(4)));

// ONE kernel, 2048 blocks x 256 threads. Block b owns output rows {2b, 2b+1}
// = one contiguous 320,000 B chunk. No cross-block dependencies at all.
//
//   waves 0,1 : compute probs for row 2b+warp entirely in registers
//               (lane i owns dim i, Ur[i,:] in 64 VGPRs, wave-uniform row
//               addresses, in-wave shfl softmax) — ~2 us, then join storing.
//   all waves : zero the chunk with NONTEMPORAL stores walking SEQUENTIALLY
//               (iter k -> contiguous 4 KB at chunk + k*4KB). R6 proved plain
//               scattered stores = 1.5 TB/s; R1 proved NT = 4 TB/s; the 6.6
//               TB/s runtime fill adds per-block contiguity — this combines
//               NT + contiguity.
//   __syncthreads (compiler drains vmcnt before s_barrier -> chunk complete)
//   waves 0,1 lanes<50: atomicAdd probs onto own rows (duplicates accumulate
//               exactly like the reference's .at[].add).
__global__ __launch_bounds__(256) void fused_all(
    const float* __restrict__ all_memory,   // [NB, NS, NH]
    const float* __restrict__ last_memory,  // [NB, NH]
    const float* __restrict__ Wr,           // [NH, NH]
    const float* __restrict__ Ur,           // [NH, NH]
    const float* __restrict__ Vr_w,         // [1, NH]
    const int* __restrict__ seq,            // [NB, NS]
    float* __restrict__ out)                // [NB, NITEM]
{
    const int bid = blockIdx.x;
    const int tid = (int)threadIdx.x;
    const int lane = tid & 63;
    const int warp = __builtin_amdgcn_readfirstlane(tid >> 6);

    float p = 0.f;
    int item = 0;
    const int row = bid * ROWS_PER_BLOCK + warp;   // valid for warp<2

    if (warp < 2) {
        // ---- compute probs for `row`, fully in-register ----
        item = (lane < NS) ? seq[row * NS + lane] : 0;

        float ur[NH];
        {
            const float* urow = Ur + lane * NH;
            #pragma unroll
            for (int h = 0; h < NH; h += 4) {
                float4 u = *(const float4*)(urow + h);
                ur[h] = u.x; ur[h + 1] = u.y; ur[h + 2] = u.z; ur[h + 3] = u.w;
            }
        }
        float lm = 0.f;
        {
            const float* lrow = last_memory + row * NH;   // wave-uniform
            const float* wrow = Wr + lane * NH;
            #pragma unroll
            for (int h = 0; h < NH; h += 4) {
                float4 w = *(const float4*)(wrow + h);
                float4 l = *(const float4*)(lrow + h);
                lm += w.x * l.x + w.y * l.y + w.z * l.z + w.w * l.w;
            }
        }
        const float vw = Vr_w[lane];
        const float* am = all_memory + (long long)row * (NS * NH);

        float myscore = 0.f;
        for (int s = 0; s < NS; ++s) {
            const float* arow = am + s * NH;              // wave-uniform
            float v0 = 0.f, v1 = 0.f, v2 = 0.f, v3 = 0.f;
            #pragma unroll
            for (int h = 0; h < NH; h += 4) {
                float4 a = *(const float4*)(arow + h);
                v0 += a.x * ur[h];
                v1 += a.y * ur[h + 1];
                v2 += a.z * ur[h + 2];
                v3 += a.w * ur[h + 3];
            }
            // Vr_b dropped: constant score shift cancels in softmax.
            float t = tanhf(lm + ((v0 + v1) + (v2 + v3))) * vw;
            #pragma unroll
            for (int off = 32; off >= 1; off >>= 1)
                t += __shfl_xor(t, off, 64);
            myscore = (lane == s) ? t : myscore;
        }

        float sc = (lane < NS) ? myscore : -INFINITY;
        float m = sc;
        #pragma unroll
        for (int off = 32; off >= 1; off >>= 1)
            m = fmaxf(m, __shfl_xor(m, off, 64));
        float e = (lane < NS) ? expf(sc - m) : 0.f;
        float d = e;
        #pragma unroll
        for (int off = 32; off >= 1; off >>= 1)
            d += __shfl_xor(d, off, 64);
        p = e / d;
    }

    // ---- zero own contiguous chunk: NT stores, sequential walk ----
    f4* chunk = (f4*)out + (long long)bid * CHUNK4;
    const f4 z = (f4)(0.0f);
    for (int i = tid; i < CHUNK4; i += 256)
        __builtin_nontemporal_store(z, chunk + i);

    __syncthreads();   // vmcnt(0) drain before barrier -> chunk fully written

    // ---- scatter onto own rows ----
    if (warp < 2 && lane < NS)
        atomicAdd(out + (long long)row * NITEM + item, p);
}

extern "C" void kernel_launch(void* const* d_in, const int* in_sizes, int n_in,
                              void* d_out, int out_size, void* d_ws, size_t ws_size,
                              hipStream_t stream) {
    const float* all_memory  = (const float*)d_in[0];
    const float* last_memory = (const float*)d_in[1];
    const float* Wr          = (const float*)d_in[2];
    const float* Ur          = (const float*)d_in[3];
    const float* Vr_w        = (const float*)d_in[4];
    // d_in[5] = Vr_b: constant shift of all scores, cancels in softmax.
    const int*   seq         = (const int*)d_in[6];
    float* out = (float*)d_out;

    fused_all<<<NBLK, 256, 0, stream>>>(all_memory, last_memory, Wr, Ur, Vr_w,
                                        seq, out);
}